// Round 4
// baseline (347.469 us; speedup 1.0000x reference)
//
#include <hip/hip_runtime.h>

#define N_ROWS 65536
#define D 256
#define K 1024
#define DECAYF 0.99f
#define OMDF 0.01f
#define EPSF 1e-5f

typedef _Float16 f16;
typedef _Float16 f16x8 __attribute__((ext_vector_type(8)));
typedef float f32x16 __attribute__((ext_vector_type(16)));

// ---------------- fused prep: zero dw/counts + codebook norms + hi/lo split ----------------
__global__ __launch_bounds__(256) void prep_kernel(const float* __restrict__ cb,
                                                   float* __restrict__ cnorm,
                                                   char* __restrict__ wsB,
                                                   float* __restrict__ dw,
                                                   float* __restrict__ counts) {
    const int tid = threadIdx.x;
    const int bid = blockIdx.x;
    const int g = bid * 256 + tid;          // 0..65535
    // zero dw (262144 floats) and counts (1024)
    *reinterpret_cast<float4*>(dw + (size_t)g * 4) = make_float4(0.f, 0.f, 0.f, 0.f);
    if (g < K) counts[g] = 0.f;
    // codebook norms: 4 rows per block
    {
        const int row = bid * 4 + (tid >> 6);
        const int lane = tid & 63;
        const float4 v = *reinterpret_cast<const float4*>(cb + (size_t)row * D + lane * 4);
        float s = v.x * v.x + v.y * v.y + v.z * v.z + v.w * v.w;
        #pragma unroll
        for (int m = 32; m; m >>= 1) s += __shfl_xor(s, m);
        if (lane == 0) cnorm[row] = s;
    }
    // hi/lo fp16 split into pre-swizzled tile layout
    {
        const int sp = g & 15;
        const int c = (g >> 4) & 255;
        const int sd = g >> 12;                  // ct*4+dk
        const int ct = sd >> 2, dk = sd & 3;
        const int sl = sp ^ (c & 7);
        const int v = sl >> 3, ks = (sl >> 1) & 3, h = sl & 1;
        const float* src = cb + (size_t)(ct * 256 + c) * D + dk * 64 + ks * 16 + h * 8;
        f16 out[8];
        #pragma unroll
        for (int e = 0; e < 8; ++e) {
            const float f = src[e];
            const f16 hi = (f16)f;
            out[e] = v ? (f16)(f - (float)hi) : hi;
        }
        *reinterpret_cast<f16x8*>(wsB + (size_t)g * 16) = *reinterpret_cast<f16x8*>(out);
    }
}

// ---------------- MFMA argmin + fused quantized-gather + one-hot writes ----------------
__global__ __launch_bounds__(256, 2) void argmin_mfma_kernel(
        const float* __restrict__ x, const float* __restrict__ cb,
        const char* __restrict__ wsB, const float* __restrict__ cnorm,
        int* __restrict__ idx_out, float* __restrict__ counts,
        float* __restrict__ quant, float* __restrict__ enc) {
    __shared__ char smem[81920];
    char* Alds = smem;
    char* Blds = smem + 16384;
    const int tid = threadIdx.x;
    const int wave = tid >> 6;
    const int lane = tid & 63;
    const int rw = wave >> 1;
    const int cw = wave & 1;
    const int l31 = lane & 31;
    const int h = lane >> 5;
    const int n0 = blockIdx.x * 64;

    float bestv[16];
    int besti[16];
    #pragma unroll
    for (int r = 0; r < 16; ++r) { bestv[r] = 3.4e38f; besti[r] = 0; }

    const int s_row = tid >> 2;
    const int s_c4 = tid & 3;

    for (int ct = 0; ct < 4; ++ct) {
        f32x16 acc[4];
        #pragma unroll
        for (int cf = 0; cf < 4; ++cf)
            #pragma unroll
            for (int r = 0; r < 16; ++r) acc[cf][r] = 0.f;

        for (int dks = 0; dks < 4; ++dks) {
            const int dk = (ct & 1) ? (3 - dks) : dks;
            __syncthreads();
            if (!(ct > 0 && dks == 0)) {
                const float4* xs = reinterpret_cast<const float4*>(
                    x + (size_t)(n0 + s_row) * D + dk * 64 + s_c4 * 16);
                float f[16];
                {
                    const float4 f0 = xs[0], f1 = xs[1], f2 = xs[2], f3 = xs[3];
                    f[0]=f0.x; f[1]=f0.y; f[2]=f0.z; f[3]=f0.w;
                    f[4]=f1.x; f[5]=f1.y; f[6]=f1.z; f[7]=f1.w;
                    f[8]=f2.x; f[9]=f2.y; f[10]=f2.z; f[11]=f2.w;
                    f[12]=f3.x; f[13]=f3.y; f[14]=f3.z; f[15]=f3.w;
                }
                f16 hi[16], lo[16];
                #pragma unroll
                for (int e = 0; e < 16; ++e) {
                    hi[e] = (f16)f[e];
                    lo[e] = (f16)(f[e] - (float)hi[e]);
                }
                const int sw = s_row & 7;
                char* Abase = Alds + s_row * 256;
                *reinterpret_cast<f16x8*>(Abase + (((s_c4 * 2 + 0) ^ sw) * 16)) = *reinterpret_cast<f16x8*>(&hi[0]);
                *reinterpret_cast<f16x8*>(Abase + (((s_c4 * 2 + 1) ^ sw) * 16)) = *reinterpret_cast<f16x8*>(&hi[8]);
                *reinterpret_cast<f16x8*>(Abase + (((8 + s_c4 * 2 + 0) ^ sw) * 16)) = *reinterpret_cast<f16x8*>(&lo[0]);
                *reinterpret_cast<f16x8*>(Abase + (((8 + s_c4 * 2 + 1) ^ sw) * 16)) = *reinterpret_cast<f16x8*>(&lo[8]);
            }
            {
                const int4* gsrc = reinterpret_cast<const int4*>(wsB + ((size_t)(ct * 4 + dk) << 16));
                int4* ldst = reinterpret_cast<int4*>(Blds);
                #pragma unroll
                for (int i = 0; i < 16; ++i) ldst[tid + i * 256] = gsrc[tid + i * 256];
            }
            __syncthreads();
            const int arow = rw * 32 + l31;
            const int asw = arow & 7;
            #pragma unroll
            for (int ks = 0; ks < 4; ++ks) {
                const int sA = ks * 2 + h;
                const f16x8 Ah = *reinterpret_cast<const f16x8*>(Alds + arow * 256 + ((sA ^ asw) * 16));
                const f16x8 Al = *reinterpret_cast<const f16x8*>(Alds + arow * 256 + (((8 + sA) ^ asw) * 16));
                #pragma unroll
                for (int cf = 0; cf < 4; ++cf) {
                    const int bcode = cw * 128 + cf * 32 + l31;
                    const char* Bbase = Blds + bcode * 256;
                    const int bsw = bcode & 7;
                    const f16x8 Bh = *reinterpret_cast<const f16x8*>(Bbase + ((sA ^ bsw) * 16));
                    const f16x8 Bl = *reinterpret_cast<const f16x8*>(Bbase + (((8 + sA) ^ bsw) * 16));
                    acc[cf] = __builtin_amdgcn_mfma_f32_32x32x16_f16(Ah, Bh, acc[cf], 0, 0, 0);
                    acc[cf] = __builtin_amdgcn_mfma_f32_32x32x16_f16(Ah, Bl, acc[cf], 0, 0, 0);
                    acc[cf] = __builtin_amdgcn_mfma_f32_32x32x16_f16(Al, Bh, acc[cf], 0, 0, 0);
                }
            }
        }
        #pragma unroll
        for (int cf = 0; cf < 4; ++cf) {
            const int code = ct * 256 + cw * 128 + cf * 32 + l31;
            const float cn = cnorm[code];
            #pragma unroll
            for (int r = 0; r < 16; ++r) {
                const float dist = cn - 2.f * acc[cf][r];
                if (dist < bestv[r]) { bestv[r] = dist; besti[r] = code; }
            }
        }
    }
    #pragma unroll
    for (int r = 0; r < 16; ++r) {
        float v = bestv[r];
        int b = besti[r];
        #pragma unroll
        for (int m = 16; m; m >>= 1) {
            const float ov = __shfl_xor(v, m);
            const int ob = __shfl_xor(b, m);
            if (ov < v || (ov == v && ob < b)) { v = ov; b = ob; }
        }
        bestv[r] = v; besti[r] = b;
    }
    __syncthreads();
    float* Sv = reinterpret_cast<float*>(smem);        // [2][64]
    int*   Si = reinterpret_cast<int*>(smem + 512);    // [2][64]
    if (l31 == 0) {
        #pragma unroll
        for (int r = 0; r < 16; ++r) {
            const int row = rw * 32 + (r & 3) + 8 * (r >> 2) + 4 * h;
            Sv[cw * 64 + row] = bestv[r];
            Si[cw * 64 + row] = besti[r];
        }
    }
    __syncthreads();
    if (tid < 64) {
        const float v0 = Sv[tid], v1 = Sv[64 + tid];
        const int b0 = Si[tid], b1 = Si[64 + tid];
        const bool take1 = (v1 < v0) || (v1 == v0 && b1 < b0);
        const int b = take1 ? b1 : b0;
        idx_out[n0 + tid] = b;
        atomicAdd(&counts[b], 1.0f);
        Si[tid] = b;   // final winners for the fused epilogue
    }
    __syncthreads();
    // fused one-hot encodings: 64 rows x 1024 floats, contiguous slab
    {
        const int k0 = tid * 4;
        #pragma unroll 4
        for (int r = 0; r < 64; ++r) {
            const int ir = Si[r];
            float4 v;
            v.x = (k0 == ir) ? 1.f : 0.f;
            v.y = (k0 + 1 == ir) ? 1.f : 0.f;
            v.z = (k0 + 2 == ir) ? 1.f : 0.f;
            v.w = (k0 + 3 == ir) ? 1.f : 0.f;
            *reinterpret_cast<float4*>(enc + (((size_t)(n0 + r)) << 10) + k0) = v;
        }
    }
    // fused quantized gather: 4 rows per iteration (one per wave)
    #pragma unroll
    for (int it = 0; it < 16; ++it) {
        const int r = it * 4 + wave;
        const int ir = Si[r];
        const float4 c = *reinterpret_cast<const float4*>(cb + (size_t)ir * D + lane * 4);
        *reinterpret_cast<float4*>(quant + (size_t)(n0 + r) * D + lane * 4) = c;
    }
}

// ---------------- cs EMA + Laplace + exclusive scan (wave-scan version) ----------------
__global__ __launch_bounds__(1024) void cs_scan_kernel(const float* __restrict__ ema_cs,
                                                       const float* __restrict__ counts,
                                                       float* __restrict__ cs_out,
                                                       int* __restrict__ cursor) {
    __shared__ float wsum[16];
    __shared__ int wisum[16];
    __shared__ float n_sh;
    const int k = threadIdx.x;
    const int wid = k >> 6;
    const int lane = k & 63;
    const float cnt = counts[k];
    const float c = ema_cs[k] * DECAYF + OMDF * cnt;
    const int ic = (int)cnt;
    // wave inclusive scan of counts
    int v = ic;
    #pragma unroll
    for (int d = 1; d < 64; d <<= 1) {
        const int t = __shfl_up(v, d);
        if (lane >= d) v += t;
    }
    // wave sum of c
    float s = c;
    #pragma unroll
    for (int m = 32; m; m >>= 1) s += __shfl_xor(s, m);
    if (lane == 63) wisum[wid] = v;
    if (lane == 0) wsum[wid] = s;
    __syncthreads();
    if (k == 0) {
        float n = 0.f;
        for (int w = 0; w < 16; ++w) n += wsum[w];
        n_sh = n;
    }
    if (wid == 0 && lane < 16) {
        int wv = wisum[lane];
        #pragma unroll
        for (int d = 1; d < 16; d <<= 1) {
            const int t = __shfl_up(wv, d);
            if (lane >= d) wv += t;
        }
        wisum[lane] = wv;  // inclusive scan of wave sums
    }
    __syncthreads();
    const float n = n_sh;
    cs_out[k] = (c + EPSF) / (n + c * EPSF) * n;
    const int wbase = (wid == 0) ? 0 : wisum[wid - 1];
    cursor[k] = wbase + v - ic;
}

// ---------------- scatter rows (and their code) by code ----------------
__global__ __launch_bounds__(256) void scatter_kernel(const int* __restrict__ idx,
                                                      int* __restrict__ cursor,
                                                      int* __restrict__ rowlist,
                                                      int* __restrict__ codelist) {
    const int n = blockIdx.x * 256 + threadIdx.x;
    const int i = idx[n];
    const int pos = atomicAdd(&cursor[i], 1);
    rowlist[pos] = n;
    codelist[pos] = i;
}

// ---------------- balanced segmented sum over sorted rowlist ----------------
__global__ __launch_bounds__(256) void chunk_sum_kernel(const float* __restrict__ x,
                                                        const int* __restrict__ rowlist,
                                                        const int* __restrict__ codelist,
                                                        float* __restrict__ dw) {
    const int wave = threadIdx.x >> 6;
    const int lane = threadIdx.x & 63;
    const int p0 = blockIdx.x * 32 + wave * 8;
    int rows[8], codes[8];
    #pragma unroll
    for (int j = 0; j < 8; ++j) {
        rows[j] = rowlist[p0 + j];
        codes[j] = codelist[p0 + j];
    }
    float4 v[8];
    #pragma unroll
    for (int j = 0; j < 8; ++j)
        v[j] = *reinterpret_cast<const float4*>(x + (size_t)rows[j] * D + lane * 4);
    float4 s = v[0];
    int cur = codes[0];
    #pragma unroll
    for (int j = 1; j < 8; ++j) {
        if (codes[j] != cur) {
            float* dst = dw + (size_t)cur * D + lane * 4;
            atomicAdd(dst + 0, s.x); atomicAdd(dst + 1, s.y);
            atomicAdd(dst + 2, s.z); atomicAdd(dst + 3, s.w);
            cur = codes[j];
            s = v[j];
        } else {
            s.x += v[j].x; s.y += v[j].y; s.z += v[j].z; s.w += v[j].w;
        }
    }
    float* dst = dw + (size_t)cur * D + lane * 4;
    atomicAdd(dst + 0, s.x); atomicAdd(dst + 1, s.y);
    atomicAdd(dst + 2, s.z); atomicAdd(dst + 3, s.w);
}

// ---------------- ema_w + new codebook ----------------
__global__ __launch_bounds__(256) void ema_kernel(const float* __restrict__ ema_w,
                                                  const float* __restrict__ dw,
                                                  const float* __restrict__ cs,
                                                  float* __restrict__ w_out,
                                                  float* __restrict__ cb_out) {
    const int e4 = blockIdx.x * blockDim.x + threadIdx.x;
    const int k = e4 >> 6;
    const float csk = cs[k];
    const float4 w = *reinterpret_cast<const float4*>(ema_w + (size_t)e4 * 4);
    const float4 d = *reinterpret_cast<const float4*>(dw + (size_t)e4 * 4);
    float4 nw, nc;
    nw.x = w.x * DECAYF + OMDF * d.x;
    nw.y = w.y * DECAYF + OMDF * d.y;
    nw.z = w.z * DECAYF + OMDF * d.z;
    nw.w = w.w * DECAYF + OMDF * d.w;
    nc.x = nw.x / csk; nc.y = nw.y / csk; nc.z = nw.z / csk; nc.w = nw.w / csk;
    *reinterpret_cast<float4*>(w_out + (size_t)e4 * 4) = nw;
    *reinterpret_cast<float4*>(cb_out + (size_t)e4 * 4) = nc;
}

extern "C" void kernel_launch(void* const* d_in, const int* in_sizes, int n_in,
                              void* d_out, int out_size, void* d_ws, size_t ws_size,
                              hipStream_t stream) {
    (void)in_sizes; (void)n_in; (void)out_size; (void)ws_size;
    const float* x      = (const float*)d_in[0];
    const float* cb     = (const float*)d_in[1];
    const float* ema_w  = (const float*)d_in[2];
    const float* ema_cs = (const float*)d_in[3];

    float* out    = (float*)d_out;
    float* quant  = out;
    float* enc    = quant + 16777216;
    float* cs_out = enc + 67108864;
    float* w_out  = cs_out + 1024;
    float* cb_out = w_out + 262144;

    float* ws       = (float*)d_ws;
    float* counts   = ws;                          // 1024 f
    float* dw       = ws + 1024;                   // 262144 f
    float* cnorm    = ws + 263168;                 // 1024 f
    int*   cursor   = (int*)(ws + 264192);         // 1024 i
    int*   idx      = (int*)(ws + 265216);         // 65536 i
    int*   rowlist  = (int*)(ws + 330752);         // 65536 i
    int*   codelist = (int*)(ws + 396288);         // 65536 i
    char*  wsB      = (char*)(ws + 461824);        // 1 MiB, 16B aligned

    prep_kernel<<<256, 256, 0, stream>>>(cb, cnorm, wsB, dw, counts);
    argmin_mfma_kernel<<<N_ROWS / 64, 256, 0, stream>>>(x, cb, wsB, cnorm, idx, counts,
                                                        quant, enc);
    cs_scan_kernel<<<1, 1024, 0, stream>>>(ema_cs, counts, cs_out, cursor);
    scatter_kernel<<<N_ROWS / 256, 256, 0, stream>>>(idx, cursor, rowlist, codelist);
    chunk_sum_kernel<<<2048, 256, 0, stream>>>(x, rowlist, codelist, dw);
    ema_kernel<<<65536 / 256, 256, 0, stream>>>(ema_w, dw, cs_out, w_out, cb_out);
}

// Round 6
// 336.067 us; speedup vs baseline: 1.0339x; 1.0339x over previous
//
#include <hip/hip_runtime.h>

#define N_ROWS 65536
#define D 256
#define K 1024
#define DECAYF 0.99f
#define OMDF 0.01f
#define EPSF 1e-5f

typedef _Float16 f16;
typedef _Float16 f16x8 __attribute__((ext_vector_type(8)));
typedef float f32x16 __attribute__((ext_vector_type(16)));
typedef float f32x4 __attribute__((ext_vector_type(4)));

// ---------------- fused prep: zero dw/counts + codebook norms + hi/lo split ----------------
__global__ __launch_bounds__(256) void prep_kernel(const float* __restrict__ cb,
                                                   float* __restrict__ cnorm,
                                                   char* __restrict__ wsB,
                                                   float* __restrict__ dw,
                                                   float* __restrict__ counts) {
    const int tid = threadIdx.x;
    const int bid = blockIdx.x;
    const int g = bid * 256 + tid;          // 0..65535
    *reinterpret_cast<float4*>(dw + (size_t)g * 4) = make_float4(0.f, 0.f, 0.f, 0.f);
    if (g < K) counts[g] = 0.f;
    {
        const int row = bid * 4 + (tid >> 6);
        const int lane = tid & 63;
        const float4 v = *reinterpret_cast<const float4*>(cb + (size_t)row * D + lane * 4);
        float s = v.x * v.x + v.y * v.y + v.z * v.z + v.w * v.w;
        #pragma unroll
        for (int m = 32; m; m >>= 1) s += __shfl_xor(s, m);
        if (lane == 0) cnorm[row] = s;
    }
    // hi/lo fp16 split into pre-swizzled tile layout (swizzle: granule ^ (code & 15))
    {
        const int sp = g & 15;
        const int c = (g >> 4) & 255;
        const int sd = g >> 12;                  // ct*4+dk
        const int ct = sd >> 2, dk = sd & 3;
        const int sl = sp ^ (c & 15);
        const int v = sl >> 3, ks = (sl >> 1) & 3, h = sl & 1;
        const float* src = cb + (size_t)(ct * 256 + c) * D + dk * 64 + ks * 16 + h * 8;
        f16 out[8];
        #pragma unroll
        for (int e = 0; e < 8; ++e) {
            const float f = src[e];
            const f16 hi = (f16)f;
            out[e] = v ? (f16)(f - (float)hi) : hi;
        }
        *reinterpret_cast<f16x8*>(wsB + (size_t)g * 16) = *reinterpret_cast<f16x8*>(out);
    }
}

// ---------------- MFMA argmin ----------------
__global__ __launch_bounds__(256, 2) void argmin_mfma_kernel(
        const float* __restrict__ x, const char* __restrict__ wsB,
        const float* __restrict__ cnorm, int* __restrict__ idx_out,
        float* __restrict__ counts) {
    __shared__ char smem[81920];
    char* Alds = smem;
    char* Blds = smem + 16384;
    const int tid = threadIdx.x;
    const int wave = tid >> 6;
    const int lane = tid & 63;
    const int rw = wave >> 1;
    const int cw = wave & 1;
    const int l31 = lane & 31;
    const int h = lane >> 5;
    const int n0 = blockIdx.x * 64;

    float bestv[16];
    int besti[16];
    #pragma unroll
    for (int r = 0; r < 16; ++r) { bestv[r] = 3.4e38f; besti[r] = 0; }

    const int s_row = tid >> 2;
    const int s_c4 = tid & 3;

    for (int ct = 0; ct < 4; ++ct) {
        f32x16 acc[4];
        #pragma unroll
        for (int cf = 0; cf < 4; ++cf)
            #pragma unroll
            for (int r = 0; r < 16; ++r) acc[cf][r] = 0.f;

        for (int dks = 0; dks < 4; ++dks) {
            const int dk = (ct & 1) ? (3 - dks) : dks;
            __syncthreads();
            if (!(ct > 0 && dks == 0)) {
                const float4* xs = reinterpret_cast<const float4*>(
                    x + (size_t)(n0 + s_row) * D + dk * 64 + s_c4 * 16);
                float f[16];
                {
                    const float4 f0 = xs[0], f1 = xs[1], f2 = xs[2], f3 = xs[3];
                    f[0]=f0.x; f[1]=f0.y; f[2]=f0.z; f[3]=f0.w;
                    f[4]=f1.x; f[5]=f1.y; f[6]=f1.z; f[7]=f1.w;
                    f[8]=f2.x; f[9]=f2.y; f[10]=f2.z; f[11]=f2.w;
                    f[12]=f3.x; f[13]=f3.y; f[14]=f3.z; f[15]=f3.w;
                }
                f16 hi[16], lo[16];
                #pragma unroll
                for (int e = 0; e < 16; ++e) {
                    hi[e] = (f16)f[e];
                    lo[e] = (f16)(f[e] - (float)hi[e]);
                }
                const int sw = s_row & 15;
                char* Abase = Alds + s_row * 256;
                *reinterpret_cast<f16x8*>(Abase + (((s_c4 * 2 + 0) ^ sw) * 16)) = *reinterpret_cast<f16x8*>(&hi[0]);
                *reinterpret_cast<f16x8*>(Abase + (((s_c4 * 2 + 1) ^ sw) * 16)) = *reinterpret_cast<f16x8*>(&hi[8]);
                *reinterpret_cast<f16x8*>(Abase + (((8 + s_c4 * 2 + 0) ^ sw) * 16)) = *reinterpret_cast<f16x8*>(&lo[0]);
                *reinterpret_cast<f16x8*>(Abase + (((8 + s_c4 * 2 + 1) ^ sw) * 16)) = *reinterpret_cast<f16x8*>(&lo[8]);
            }
            {
                const int4* gsrc = reinterpret_cast<const int4*>(wsB + ((size_t)(ct * 4 + dk) << 16));
                int4* ldst = reinterpret_cast<int4*>(Blds);
                #pragma unroll
                for (int i = 0; i < 16; ++i) ldst[tid + i * 256] = gsrc[tid + i * 256];
            }
            __syncthreads();
            const int arow = rw * 32 + l31;
            const int asw = arow & 15;
            #pragma unroll
            for (int ks = 0; ks < 4; ++ks) {
                const int sA = ks * 2 + h;
                const f16x8 Ah = *reinterpret_cast<const f16x8*>(Alds + arow * 256 + ((sA ^ asw) * 16));
                const f16x8 Al = *reinterpret_cast<const f16x8*>(Alds + arow * 256 + (((8 + sA) ^ asw) * 16));
                #pragma unroll
                for (int cf = 0; cf < 4; ++cf) {
                    const int bcode = cw * 128 + cf * 32 + l31;
                    const char* Bbase = Blds + bcode * 256;
                    const int bsw = bcode & 15;
                    const f16x8 Bh = *reinterpret_cast<const f16x8*>(Bbase + ((sA ^ bsw) * 16));
                    const f16x8 Bl = *reinterpret_cast<const f16x8*>(Bbase + (((8 + sA) ^ bsw) * 16));
                    acc[cf] = __builtin_amdgcn_mfma_f32_32x32x16_f16(Ah, Bh, acc[cf], 0, 0, 0);
                    acc[cf] = __builtin_amdgcn_mfma_f32_32x32x16_f16(Ah, Bl, acc[cf], 0, 0, 0);
                    acc[cf] = __builtin_amdgcn_mfma_f32_32x32x16_f16(Al, Bh, acc[cf], 0, 0, 0);
                }
            }
        }
        #pragma unroll
        for (int cf = 0; cf < 4; ++cf) {
            const int code = ct * 256 + cw * 128 + cf * 32 + l31;
            const float cn = cnorm[code];
            #pragma unroll
            for (int r = 0; r < 16; ++r) {
                const float dist = cn - 2.f * acc[cf][r];
                if (dist < bestv[r]) { bestv[r] = dist; besti[r] = code; }
            }
        }
    }
    #pragma unroll
    for (int r = 0; r < 16; ++r) {
        float v = bestv[r];
        int b = besti[r];
        #pragma unroll
        for (int m = 16; m; m >>= 1) {
            const float ov = __shfl_xor(v, m);
            const int ob = __shfl_xor(b, m);
            if (ov < v || (ov == v && ob < b)) { v = ov; b = ob; }
        }
        bestv[r] = v; besti[r] = b;
    }
    __syncthreads();
    float* Sv = reinterpret_cast<float*>(smem);
    int*   Si = reinterpret_cast<int*>(smem + 512);
    if (l31 == 0) {
        #pragma unroll
        for (int r = 0; r < 16; ++r) {
            const int row = rw * 32 + (r & 3) + 8 * (r >> 2) + 4 * h;
            Sv[cw * 64 + row] = bestv[r];
            Si[cw * 64 + row] = besti[r];
        }
    }
    __syncthreads();
    if (tid < 64) {
        const float v0 = Sv[tid], v1 = Sv[64 + tid];
        const int b0 = Si[tid], b1 = Si[64 + tid];
        const bool take1 = (v1 < v0) || (v1 == v0 && b1 < b0);
        const int b = take1 ? b1 : b0;
        idx_out[n0 + tid] = b;
        atomicAdd(&counts[b], 1.0f);
    }
}

// ---------------- quantized gather (nontemporal stores) ----------------
__global__ __launch_bounds__(256) void quant_kernel(const float* __restrict__ cb,
                                                    const int* __restrict__ idx,
                                                    float* __restrict__ quant) {
    const int n = blockIdx.x * 4 + (threadIdx.x >> 6);
    const int lane = threadIdx.x & 63;
    const int i = idx[n];
    const f32x4 c = *reinterpret_cast<const f32x4*>(cb + (size_t)i * D + lane * 4);
    __builtin_nontemporal_store(c, reinterpret_cast<f32x4*>(quant + (size_t)n * D + lane * 4));
}

// ---------------- one-hot encodings (nontemporal stores) ----------------
__global__ __launch_bounds__(256) void enc_kernel(const int* __restrict__ idx,
                                                  float* __restrict__ enc) {
    const int total = N_ROWS * (K / 4);
    for (int g = blockIdx.x * blockDim.x + threadIdx.x; g < total;
         g += gridDim.x * blockDim.x) {
        const int n = g >> 8;
        const int k0 = (g & 255) * 4;
        const int i = idx[n];
        f32x4 v;
        v[0] = (k0 == i) ? 1.f : 0.f;
        v[1] = (k0 + 1 == i) ? 1.f : 0.f;
        v[2] = (k0 + 2 == i) ? 1.f : 0.f;
        v[3] = (k0 + 3 == i) ? 1.f : 0.f;
        __builtin_nontemporal_store(v, reinterpret_cast<f32x4*>(enc + (size_t)g * 4));
    }
}

// ---------------- cs EMA + Laplace + exclusive scan (wave-scan) ----------------
__global__ __launch_bounds__(1024) void cs_scan_kernel(const float* __restrict__ ema_cs,
                                                       const float* __restrict__ counts,
                                                       float* __restrict__ cs_out,
                                                       int* __restrict__ cursor) {
    __shared__ float wsum[16];
    __shared__ int wisum[16];
    __shared__ float n_sh;
    const int k = threadIdx.x;
    const int wid = k >> 6;
    const int lane = k & 63;
    const float cnt = counts[k];
    const float c = ema_cs[k] * DECAYF + OMDF * cnt;
    const int ic = (int)cnt;
    int v = ic;
    #pragma unroll
    for (int d = 1; d < 64; d <<= 1) {
        const int t = __shfl_up(v, d);
        if (lane >= d) v += t;
    }
    float s = c;
    #pragma unroll
    for (int m = 32; m; m >>= 1) s += __shfl_xor(s, m);
    if (lane == 63) wisum[wid] = v;
    if (lane == 0) wsum[wid] = s;
    __syncthreads();
    if (k == 0) {
        float n = 0.f;
        for (int w = 0; w < 16; ++w) n += wsum[w];
        n_sh = n;
    }
    if (wid == 0 && lane < 16) {
        int wv = wisum[lane];
        #pragma unroll
        for (int d = 1; d < 16; d <<= 1) {
            const int t = __shfl_up(wv, d);
            if (lane >= d) wv += t;
        }
        wisum[lane] = wv;
    }
    __syncthreads();
    const float n = n_sh;
    cs_out[k] = (c + EPSF) / (n + c * EPSF) * n;
    const int wbase = (wid == 0) ? 0 : wisum[wid - 1];
    cursor[k] = wbase + v - ic;
}

// ---------------- scatter rows (and their code) by code ----------------
__global__ __launch_bounds__(256) void scatter_kernel(const int* __restrict__ idx,
                                                      int* __restrict__ cursor,
                                                      int* __restrict__ rowlist,
                                                      int* __restrict__ codelist) {
    const int n = blockIdx.x * 256 + threadIdx.x;
    const int i = idx[n];
    const int pos = atomicAdd(&cursor[i], 1);
    rowlist[pos] = n;
    codelist[pos] = i;
}

// ---------------- balanced segmented sum over sorted rowlist ----------------
__global__ __launch_bounds__(256) void chunk_sum_kernel(const float* __restrict__ x,
                                                        const int* __restrict__ rowlist,
                                                        const int* __restrict__ codelist,
                                                        float* __restrict__ dw) {
    const int wave = threadIdx.x >> 6;
    const int lane = threadIdx.x & 63;
    const int p0 = blockIdx.x * 32 + wave * 8;
    int rows[8], codes[8];
    #pragma unroll
    for (int j = 0; j < 8; ++j) {
        rows[j] = rowlist[p0 + j];
        codes[j] = codelist[p0 + j];
    }
    float4 v[8];
    #pragma unroll
    for (int j = 0; j < 8; ++j)
        v[j] = *reinterpret_cast<const float4*>(x + (size_t)rows[j] * D + lane * 4);
    float4 s = v[0];
    int cur = codes[0];
    #pragma unroll
    for (int j = 1; j < 8; ++j) {
        if (codes[j] != cur) {
            float* dst = dw + (size_t)cur * D + lane * 4;
            atomicAdd(dst + 0, s.x); atomicAdd(dst + 1, s.y);
            atomicAdd(dst + 2, s.z); atomicAdd(dst + 3, s.w);
            cur = codes[j];
            s = v[j];
        } else {
            s.x += v[j].x; s.y += v[j].y; s.z += v[j].z; s.w += v[j].w;
        }
    }
    float* dst = dw + (size_t)cur * D + lane * 4;
    atomicAdd(dst + 0, s.x); atomicAdd(dst + 1, s.y);
    atomicAdd(dst + 2, s.z); atomicAdd(dst + 3, s.w);
}

// ---------------- ema_w + new codebook ----------------
__global__ __launch_bounds__(256) void ema_kernel(const float* __restrict__ ema_w,
                                                  const float* __restrict__ dw,
                                                  const float* __restrict__ cs,
                                                  float* __restrict__ w_out,
                                                  float* __restrict__ cb_out) {
    const int e4 = blockIdx.x * blockDim.x + threadIdx.x;
    const int k = e4 >> 6;
    const float csk = cs[k];
    const float4 w = *reinterpret_cast<const float4*>(ema_w + (size_t)e4 * 4);
    const float4 d = *reinterpret_cast<const float4*>(dw + (size_t)e4 * 4);
    float4 nw, nc;
    nw.x = w.x * DECAYF + OMDF * d.x;
    nw.y = w.y * DECAYF + OMDF * d.y;
    nw.z = w.z * DECAYF + OMDF * d.z;
    nw.w = w.w * DECAYF + OMDF * d.w;
    nc.x = nw.x / csk; nc.y = nw.y / csk; nc.z = nw.z / csk; nc.w = nw.w / csk;
    *reinterpret_cast<float4*>(w_out + (size_t)e4 * 4) = nw;
    *reinterpret_cast<float4*>(cb_out + (size_t)e4 * 4) = nc;
}

extern "C" void kernel_launch(void* const* d_in, const int* in_sizes, int n_in,
                              void* d_out, int out_size, void* d_ws, size_t ws_size,
                              hipStream_t stream) {
    (void)in_sizes; (void)n_in; (void)out_size; (void)ws_size;
    const float* x      = (const float*)d_in[0];
    const float* cb     = (const float*)d_in[1];
    const float* ema_w  = (const float*)d_in[2];
    const float* ema_cs = (const float*)d_in[3];

    float* out    = (float*)d_out;
    float* quant  = out;
    float* enc    = quant + 16777216;
    float* cs_out = enc + 67108864;
    float* w_out  = cs_out + 1024;
    float* cb_out = w_out + 262144;

    float* ws       = (float*)d_ws;
    float* counts   = ws;                          // 1024 f
    float* dw       = ws + 1024;                   // 262144 f
    float* cnorm    = ws + 263168;                 // 1024 f
    int*   cursor   = (int*)(ws + 264192);         // 1024 i
    int*   idx      = (int*)(ws + 265216);         // 65536 i
    int*   rowlist  = (int*)(ws + 330752);         // 65536 i
    int*   codelist = (int*)(ws + 396288);         // 65536 i
    char*  wsB      = (char*)(ws + 461824);        // 1 MiB, 16B aligned

    prep_kernel<<<256, 256, 0, stream>>>(cb, cnorm, wsB, dw, counts);
    argmin_mfma_kernel<<<N_ROWS / 64, 256, 0, stream>>>(x, wsB, cnorm, idx, counts);
    quant_kernel<<<N_ROWS / 4, 256, 0, stream>>>(cb, idx, quant);
    enc_kernel<<<2048, 256, 0, stream>>>(idx, enc);
    cs_scan_kernel<<<1, 1024, 0, stream>>>(ema_cs, counts, cs_out, cursor);
    scatter_kernel<<<N_ROWS / 256, 256, 0, stream>>>(idx, cursor, rowlist, codelist);
    chunk_sum_kernel<<<2048, 256, 0, stream>>>(x, rowlist, codelist, dw);
    ema_kernel<<<65536 / 256, 256, 0, stream>>>(ema_w, dw, cs_out, w_out, cb_out);
}